// Round 9
// baseline (37.836 us; speedup 1.0000x reference)
//
#include <hip/hip_runtime.h>

// query:          [N=8, C=640, H=48, W=48] f32
// dynamic_filter: [N=8, 2304, 9, 1] f32   (per-pixel 3x3 taps, shared over C)
// out1 = relu(dynamic 3x3 conv): [8,640,48,48] f32
// out2 = zeros_like(dynamic_filter)
//
// R9: R8 is latency-exposed (all throughput models give 2-11us vs 20.5
// measured). Attack: (1) CH=8 -> 7680 waves, LDS-capped 20 waves/CU (was 15)
// and half the serial per-wave channel chain; (2) prefetch depth 4 (12 loads
// in flight); (3) launch_bounds(256,5) to fit 5 blocks/CU.
#define N_   8
#define C_   640
#define H_   48
#define W_   48
#define K_   9
#define CH   8
#define NCC  (C_ / CH)              // 80
#define BLK  256                    // 16 rows x 16 lanes (12 active)
#define HB   3                      // 48 rows / 16 rows-per-block
#define NBLK (N_ * NCC * HB)        // 1920 = 8 * 240 (XCD-bijective)
#define DF_F4   1728                // 16 rows * 48 px * 9 taps / 4
#define OUT1_ELEMS ((size_t)N_ * C_ * H_ * W_)   // 11,796,480
#define OUT2_ELEMS ((size_t)N_ * H_ * W_ * K_)   //    165,888
#define DEPTH 4

typedef float f4 __attribute__((ext_vector_type(4)));

__global__ __launch_bounds__(BLK, 5) void dynconv(
    const float* __restrict__ q,
    const float* __restrict__ df,
    float* __restrict__ out)
{
    __shared__ f4 sdf[DF_F4];       // 27,648 B

    const int tid = threadIdx.x;
    const int bid = blockIdx.x;
    // XCD swizzle: 240 consecutive work-ids per XCD = one full n (df L2-resident)
    const int swz = (bid & 7) * (NBLK / 8) + (bid >> 3);

    // ---- zero out2 (1920*256 covers 165,888 with first 648 blocks) ----
    {
        size_t g = (size_t)bid * BLK + tid;
        if (g < OUT2_ELEMS) out[OUT1_ELEMS + g] = 0.f;
    }

    const int p     = tid & 15;     // lane-in-row; active if p < 12
    const int rowid = tid >> 4;     // 0..15 rows per block

    const int hb = swz % HB;
    const int cc = (swz / HB) % NCC;
    const int n  = swz / (HB * NCC);
    const int h  = hb * 16 + rowid;
    const int w0 = p * 4;
    const int c0 = cc * CH;

    // ---- stage df slice: block-coalesced global loads issued FIRST ----
    const f4* dfg = (const f4*)(df + (size_t)n * (H_ * W_ * K_)
                                   + (size_t)hb * 16 * W_ * K_);
    f4 stg[7];
#pragma unroll
    for (int i = 0; i < 7; ++i) {
        int idx = tid + i * BLK;
        if (idx < DF_F4) stg[i] = dfg[idx];     // wave-uniform predicate
    }

    // ---- row-clamped offsets; taps absorb all boundary zeroing ----
    int roff[3];
#pragma unroll
    for (int dy = 0; dy < 3; ++dy) {
        int r  = h + dy - 1;
        int rc = min(max(r, 0), H_ - 1);
        roff[dy] = (rc - h) * W_;
    }

    const size_t plane = (size_t)H_ * W_;
    const float* qbase = q   + ((size_t)(n * C_ + c0)) * plane + h * W_ + w0;
    float*       obase = out + ((size_t)(n * C_ + c0)) * plane + h * W_ + w0;

    // ---- prologue: channels 0..3 in flight (active lanes only) ----
    f4 m[DEPTH][3];
    if (p < 12) {
#pragma unroll
        for (int d = 0; d < DEPTH; ++d) {
            const float* qp = qbase + (size_t)d * plane;
#pragma unroll
            for (int dy = 0; dy < 3; ++dy) m[d][dy] = *(const f4*)(qp + roff[dy]);
        }
    }

    // ---- LDS writes, then barrier ----
#pragma unroll
    for (int i = 0; i < 7; ++i) {
        int idx = tid + i * BLK;
        if (idx < DF_F4) sdf[idx] = stg[i];
    }
    __syncthreads();

    if (p >= 12) return;            // idle lanes done (past the barrier)

    // ---- taps from LDS: 9x ds_read_b128 ----
    float f[36];
    {
        const f4* tp = &sdf[rowid * 108 + p * 9];
#pragma unroll
        for (int i = 0; i < 9; ++i) {
            f4 v = tp[i];
            f[4*i+0] = v.x; f[4*i+1] = v.y; f[4*i+2] = v.z; f[4*i+3] = v.w;
        }
    }

    const float tm = (h == 0)      ? 0.f : 1.f;   // top row
    const float bm = (h == H_ - 1) ? 0.f : 1.f;   // bottom row
    const float lm = (p == 0)      ? 0.f : 1.f;   // image left  (w0==0)
    const float rm = (p == 11)     ? 0.f : 1.f;   // image right (w0==44)
#pragma unroll
    for (int px = 0; px < 4; ++px) {
        f[px*9+0] *= tm; f[px*9+1] *= tm; f[px*9+2] *= tm;
        f[px*9+6] *= bm; f[px*9+7] *= bm; f[px*9+8] *= bm;
    }
    f[ 0] *= lm; f[ 3] *= lm; f[ 6] *= lm;   // pixel0 left column
    f[29] *= rm; f[32] *= rm; f[35] *= rm;   // pixel3 right column

    // ---- channel loop: 3 f4 loads + 6 shuffles + 36 FMA + 1 f4 store ----
#pragma unroll
    for (int ci = 0; ci < CH; ++ci) {
        asm volatile("" : "+v"(m[0][0]), "+v"(m[0][1]), "+v"(m[0][2]));

        float lft[3], rgt[3];
#pragma unroll
        for (int dy = 0; dy < 3; ++dy) {
            lft[dy] = __shfl_up(m[0][dy].w, 1);    // neighbor strip's last px
            rgt[dy] = __shfl_down(m[0][dy].x, 1);  // neighbor strip's first px
        }

        f4 acc = (f4){0.f, 0.f, 0.f, 0.f};
#pragma unroll
        for (int dy = 0; dy < 3; ++dy) {
            const int fb = dy * 3;
            const f4 mm = m[0][dy];
            acc.x = fmaf(f[ 0 + fb], lft[dy], acc.x);
            acc.x = fmaf(f[ 1 + fb], mm.x,    acc.x);
            acc.x = fmaf(f[ 2 + fb], mm.y,    acc.x);

            acc.y = fmaf(f[ 9 + fb], mm.x,    acc.y);
            acc.y = fmaf(f[10 + fb], mm.y,    acc.y);
            acc.y = fmaf(f[11 + fb], mm.z,    acc.y);

            acc.z = fmaf(f[18 + fb], mm.y,    acc.z);
            acc.z = fmaf(f[19 + fb], mm.z,    acc.z);
            acc.z = fmaf(f[20 + fb], mm.w,    acc.z);

            acc.w = fmaf(f[27 + fb], mm.z,    acc.w);
            acc.w = fmaf(f[28 + fb], mm.w,    acc.w);
            acc.w = fmaf(f[29 + fb], rgt[dy], acc.w);
        }
        acc.x = fmaxf(acc.x, 0.f);
        acc.y = fmaxf(acc.y, 0.f);
        acc.z = fmaxf(acc.z, 0.f);
        acc.w = fmaxf(acc.w, 0.f);
        *(f4*)(obase + (size_t)ci * plane) = acc;

        // rotate depth-4 pipeline (SSA rename) + issue ci+DEPTH
        if (ci + 1 < CH) {
#pragma unroll
            for (int d = 0; d < DEPTH - 1; ++d)
#pragma unroll
                for (int dy = 0; dy < 3; ++dy) m[d][dy] = m[d + 1][dy];
            if (ci + DEPTH < CH) {
                const float* qp = qbase + (size_t)(ci + DEPTH) * plane;
#pragma unroll
                for (int dy = 0; dy < 3; ++dy)
                    m[DEPTH - 1][dy] = *(const f4*)(qp + roff[dy]);
            }
        }
    }
}

extern "C" void kernel_launch(void* const* d_in, const int* in_sizes, int n_in,
                              void* d_out, int out_size, void* d_ws, size_t ws_size,
                              hipStream_t stream)
{
    const float* q  = (const float*)d_in[0];
    const float* df = (const float*)d_in[1];
    float* out = (float*)d_out;

    dynconv<<<NBLK, BLK, 0, stream>>>(q, df, out);
}

// Round 10
// 21.261 us; speedup vs baseline: 1.7796x; 1.7796x over previous
//
#include <hip/hip_runtime.h>

// query:          [N=8, C=640, H=48, W=48] f32
// dynamic_filter: [N=8, 2304, 9, 1] f32   (per-pixel 3x3 taps, shared over C)
// out1 = relu(per-pixel 3x3 dyn conv, shared over C): [8,640,48,48] f32
// out2 = zeros_like(dynamic_filter)
//
// R10: R9's regression was self-inflicted (VGPR squeezed to 48 by
// launch_bounds(256,5); df L2-thrash from hb-fastest ordering). Keep CH=8
// (30 waves/CU of work) but: launch_bounds(128,4) -> ~100 VGPR allowed;
// cc-fastest XCD ordering -> consecutive blocks reuse the SAME 13.8KB df
// slice + 1.2MB q window in L2; 2-wave blocks -> staggered staging.
#define N_   8
#define C_   640
#define H_   48
#define W_   48
#define K_   9
#define CH   8
#define NCC  (C_ / CH)              // 80
#define BLK  128                    // 8 rows x 16 lanes (12 active)
#define RPB  8                      // rows per block
#define HB   (H_ / RPB)             // 6
#define NBLK (N_ * NCC * HB)        // 3840 = 8 XCD * 480
#define DF_F4   864                 // 8 rows * 48 px * 9 taps / 4
#define OUT1_ELEMS ((size_t)N_ * C_ * H_ * W_)   // 11,796,480
#define OUT2_ELEMS ((size_t)N_ * H_ * W_ * K_)   //    165,888
#define DEPTH 3

typedef float f4 __attribute__((ext_vector_type(4)));

__global__ __launch_bounds__(BLK, 4) void dynconv(
    const float* __restrict__ q,
    const float* __restrict__ df,
    float* __restrict__ out)
{
    __shared__ f4 sdf[DF_F4];       // 13,824 B

    const int tid = threadIdx.x;
    const int bid = blockIdx.x;
    // XCD swizzle, cc-FASTEST within an XCD: consecutive blocks on one XCD
    // share (n,hb) -> df slice (13.8KB) and q window (1.2MB) stay L2-hot.
    const int swz = (bid & 7) * (NBLK / 8) + (bid >> 3);
    const int cc  = swz % NCC;              // fastest
    const int hb  = (swz / NCC) % HB;
    const int n   = swz / (NCC * HB);       // one n per XCD

    // ---- zero out2 (3840*128 = 491,520 >= 165,888) ----
    {
        size_t g = (size_t)bid * BLK + tid;
        if (g < OUT2_ELEMS) out[OUT1_ELEMS + g] = 0.f;
    }

    const int p     = tid & 15;     // lane-in-row; active if p < 12
    const int rowid = tid >> 4;     // 0..7 rows per block
    const int h  = hb * RPB + rowid;
    const int w0 = p * 4;
    const int c0 = cc * CH;

    // ---- stage df slice: block-coalesced global loads issued FIRST ----
    const f4* dfg = (const f4*)(df + (size_t)n * (H_ * W_ * K_)
                                   + (size_t)hb * RPB * W_ * K_);
    f4 stg[7];
#pragma unroll
    for (int i = 0; i < 7; ++i) {
        int idx = tid + i * BLK;
        if (idx < DF_F4) stg[i] = dfg[idx];     // wave-uniform predicate
    }

    // ---- row-clamped offsets; taps absorb all boundary zeroing ----
    int roff[3];
#pragma unroll
    for (int dy = 0; dy < 3; ++dy) {
        int r  = h + dy - 1;
        int rc = min(max(r, 0), H_ - 1);
        roff[dy] = (rc - h) * W_;
    }

    const size_t plane = (size_t)H_ * W_;
    const float* qbase = q   + ((size_t)(n * C_ + c0)) * plane + h * W_ + w0;
    float*       obase = out + ((size_t)(n * C_ + c0)) * plane + h * W_ + w0;

    // ---- prologue: channels 0..2 in flight (active lanes only) ----
    f4 m[DEPTH][3];
    if (p < 12) {
#pragma unroll
        for (int d = 0; d < DEPTH; ++d) {
            const float* qp = qbase + (size_t)d * plane;
#pragma unroll
            for (int dy = 0; dy < 3; ++dy) m[d][dy] = *(const f4*)(qp + roff[dy]);
        }
    }

    // ---- LDS writes, then barrier (couples only 2 waves) ----
#pragma unroll
    for (int i = 0; i < 7; ++i) {
        int idx = tid + i * BLK;
        if (idx < DF_F4) sdf[idx] = stg[i];
    }
    __syncthreads();

    if (p >= 12) return;            // idle lanes done (past the barrier)

    // ---- taps from LDS: 9x ds_read_b128 ----
    float f[36];
    {
        const f4* tp = &sdf[rowid * 108 + p * 9];
#pragma unroll
        for (int i = 0; i < 9; ++i) {
            f4 v = tp[i];
            f[4*i+0] = v.x; f[4*i+1] = v.y; f[4*i+2] = v.z; f[4*i+3] = v.w;
        }
    }

    const float tm = (h == 0)      ? 0.f : 1.f;   // top image row
    const float bm = (h == H_ - 1) ? 0.f : 1.f;   // bottom image row
    const float lm = (p == 0)      ? 0.f : 1.f;   // image left  (w0==0)
    const float rm = (p == 11)     ? 0.f : 1.f;   // image right (w0==44)
#pragma unroll
    for (int px = 0; px < 4; ++px) {
        f[px*9+0] *= tm; f[px*9+1] *= tm; f[px*9+2] *= tm;
        f[px*9+6] *= bm; f[px*9+7] *= bm; f[px*9+8] *= bm;
    }
    f[ 0] *= lm; f[ 3] *= lm; f[ 6] *= lm;   // pixel0 left column
    f[29] *= rm; f[32] *= rm; f[35] *= rm;   // pixel3 right column

    // ---- channel loop: 3 f4 loads + 6 shuffles + 36 FMA + 1 f4 store ----
#pragma unroll
    for (int ci = 0; ci < CH; ++ci) {
        asm volatile("" : "+v"(m[0][0]), "+v"(m[0][1]), "+v"(m[0][2]));

        float lft[3], rgt[3];
#pragma unroll
        for (int dy = 0; dy < 3; ++dy) {
            lft[dy] = __shfl_up(m[0][dy].w, 1);    // neighbor strip's last px
            rgt[dy] = __shfl_down(m[0][dy].x, 1);  // neighbor strip's first px
        }

        f4 acc = (f4){0.f, 0.f, 0.f, 0.f};
#pragma unroll
        for (int dy = 0; dy < 3; ++dy) {
            const int fb = dy * 3;
            const f4 mm = m[0][dy];
            acc.x = fmaf(f[ 0 + fb], lft[dy], acc.x);
            acc.x = fmaf(f[ 1 + fb], mm.x,    acc.x);
            acc.x = fmaf(f[ 2 + fb], mm.y,    acc.x);

            acc.y = fmaf(f[ 9 + fb], mm.x,    acc.y);
            acc.y = fmaf(f[10 + fb], mm.y,    acc.y);
            acc.y = fmaf(f[11 + fb], mm.z,    acc.y);

            acc.z = fmaf(f[18 + fb], mm.y,    acc.z);
            acc.z = fmaf(f[19 + fb], mm.z,    acc.z);
            acc.z = fmaf(f[20 + fb], mm.w,    acc.z);

            acc.w = fmaf(f[27 + fb], mm.z,    acc.w);
            acc.w = fmaf(f[28 + fb], mm.w,    acc.w);
            acc.w = fmaf(f[29 + fb], rgt[dy], acc.w);
        }
        acc.x = fmaxf(acc.x, 0.f);
        acc.y = fmaxf(acc.y, 0.f);
        acc.z = fmaxf(acc.z, 0.f);
        acc.w = fmaxf(acc.w, 0.f);
        *(f4*)(obase + (size_t)ci * plane) = acc;

        // rotate depth-3 pipeline (SSA rename) + issue ci+DEPTH
        if (ci + 1 < CH) {
#pragma unroll
            for (int d = 0; d < DEPTH - 1; ++d)
#pragma unroll
                for (int dy = 0; dy < 3; ++dy) m[d][dy] = m[d + 1][dy];
            if (ci + DEPTH < CH) {
                const float* qp = qbase + (size_t)(ci + DEPTH) * plane;
#pragma unroll
                for (int dy = 0; dy < 3; ++dy)
                    m[DEPTH - 1][dy] = *(const f4*)(qp + roff[dy]);
            }
        }
    }
}

extern "C" void kernel_launch(void* const* d_in, const int* in_sizes, int n_in,
                              void* d_out, int out_size, void* d_ws, size_t ws_size,
                              hipStream_t stream)
{
    const float* q  = (const float*)d_in[0];
    const float* df = (const float*)d_in[1];
    float* out = (float*)d_out;

    dynconv<<<NBLK, BLK, 0, stream>>>(q, df, out);
}

// Round 11
// 20.594 us; speedup vs baseline: 1.8373x; 1.0324x over previous
//
#include <hip/hip_runtime.h>

// query:          [N=8, C=640, H=48, W=48] f32
// dynamic_filter: [N=8, 2304, 9, 1] f32   (per-pixel 3x3 taps, shared over C)
// out1 = relu(per-pixel 3x3 dyn conv, shared over C): [8,640,48,48] f32
// out2 = zeros_like(dynamic_filter)
//
// R11 = R8 (best: 20.5us) + two isolated changes:
//  (a) nontemporal stores for out1/out2: 47MB of write-allocate was evicting
//      the q/df read window from L2;
//  (b) prefetch depth 3->4 (12 q-loads in flight; ~95 VGPR fits the 128 cap).
// Decision rule: if this lands >=19.5us, three structures + models agree the
// kernel is at its ~11us memory floor (+~9us harness fixed overhead) -> done.
#define N_   8
#define C_   640
#define H_   48
#define W_   48
#define K_   9
#define CH   16
#define NCC  (C_ / CH)              // 40
#define BLK  256                    // 16 rows x 16 lanes (12 active)
#define HB   3                      // 48 rows / 16 rows-per-block
#define NBLK (N_ * NCC * HB)        // 960 = 8 * 120 (XCD-bijective)
#define DF_F4   1728                // 16 rows * 48 px * 9 taps / 4
#define OUT1_ELEMS ((size_t)N_ * C_ * H_ * W_)   // 11,796,480
#define OUT2_ELEMS ((size_t)N_ * H_ * W_ * K_)   //    165,888
#define DEPTH 4

typedef float f4 __attribute__((ext_vector_type(4)));

__global__ __launch_bounds__(BLK, 4) void dynconv(
    const float* __restrict__ q,
    const float* __restrict__ df,
    float* __restrict__ out)
{
    __shared__ f4 sdf[DF_F4];       // 27,648 B

    const int tid = threadIdx.x;
    const int bid = blockIdx.x;
    // XCD swizzle: 120 consecutive work-ids per XCD = one full n (df L2-resident)
    const int swz = (bid & 7) * (NBLK / 8) + (bid >> 3);

    const int p     = tid & 15;     // lane-in-row; active if p < 12
    const int rowid = tid >> 4;     // 0..15 rows per block

    const int hb = swz % HB;
    const int cc = (swz / HB) % NCC;
    const int n  = swz / (HB * NCC);
    const int h  = hb * 16 + rowid;
    const int w0 = p * 4;
    const int c0 = cc * CH;

    // ---- stage df slice: block-coalesced global loads issued FIRST ----
    const f4* dfg = (const f4*)(df + (size_t)n * (H_ * W_ * K_)
                                   + (size_t)hb * 16 * W_ * K_);
    f4 stg[7];
#pragma unroll
    for (int i = 0; i < 7; ++i) {
        int idx = tid + i * BLK;
        if (idx < DF_F4) stg[i] = dfg[idx];     // wave-uniform predicate
    }

    // ---- row-clamped offsets; taps absorb all boundary zeroing ----
    int roff[3];
#pragma unroll
    for (int dy = 0; dy < 3; ++dy) {
        int r  = h + dy - 1;
        int rc = min(max(r, 0), H_ - 1);
        roff[dy] = (rc - h) * W_;
    }

    const size_t plane = (size_t)H_ * W_;
    const float* qbase = q   + ((size_t)(n * C_ + c0)) * plane + h * W_ + w0;
    float*       obase = out + ((size_t)(n * C_ + c0)) * plane + h * W_ + w0;

    // ---- prologue: channels 0..3 in flight (active lanes only) ----
    f4 m[DEPTH][3];
    if (p < 12) {
#pragma unroll
        for (int d = 0; d < DEPTH; ++d) {
            const float* qp = qbase + (size_t)d * plane;
#pragma unroll
            for (int dy = 0; dy < 3; ++dy) m[d][dy] = *(const f4*)(qp + roff[dy]);
        }
    }

    // ---- zero out2 (NT; no L2 pollution) ----
    {
        size_t g = (size_t)bid * BLK + tid;
        if (g < OUT2_ELEMS)
            __builtin_nontemporal_store(0.f, out + OUT1_ELEMS + g);
    }

    // ---- LDS writes, then barrier ----
#pragma unroll
    for (int i = 0; i < 7; ++i) {
        int idx = tid + i * BLK;
        if (idx < DF_F4) sdf[idx] = stg[i];
    }
    __syncthreads();

    if (p >= 12) return;            // idle lanes done (past the barrier)

    // ---- taps from LDS: 9x ds_read_b128 ----
    float f[36];
    {
        const f4* tp = &sdf[rowid * 108 + p * 9];
#pragma unroll
        for (int i = 0; i < 9; ++i) {
            f4 v = tp[i];
            f[4*i+0] = v.x; f[4*i+1] = v.y; f[4*i+2] = v.z; f[4*i+3] = v.w;
        }
    }

    const float tm = (h == 0)      ? 0.f : 1.f;   // top image row
    const float bm = (h == H_ - 1) ? 0.f : 1.f;   // bottom image row
    const float lm = (p == 0)      ? 0.f : 1.f;   // image left  (w0==0)
    const float rm = (p == 11)     ? 0.f : 1.f;   // image right (w0==44)
#pragma unroll
    for (int px = 0; px < 4; ++px) {
        f[px*9+0] *= tm; f[px*9+1] *= tm; f[px*9+2] *= tm;
        f[px*9+6] *= bm; f[px*9+7] *= bm; f[px*9+8] *= bm;
    }
    f[ 0] *= lm; f[ 3] *= lm; f[ 6] *= lm;   // pixel0 left column
    f[29] *= rm; f[32] *= rm; f[35] *= rm;   // pixel3 right column

    // ---- channel loop: 3 f4 loads + 6 shuffles + 36 FMA + 1 NT f4 store ----
#pragma unroll
    for (int ci = 0; ci < CH; ++ci) {
        asm volatile("" : "+v"(m[0][0]), "+v"(m[0][1]), "+v"(m[0][2]));

        float lft[3], rgt[3];
#pragma unroll
        for (int dy = 0; dy < 3; ++dy) {
            lft[dy] = __shfl_up(m[0][dy].w, 1);    // neighbor strip's last px
            rgt[dy] = __shfl_down(m[0][dy].x, 1);  // neighbor strip's first px
        }

        f4 acc = (f4){0.f, 0.f, 0.f, 0.f};
#pragma unroll
        for (int dy = 0; dy < 3; ++dy) {
            const int fb = dy * 3;
            const f4 mm = m[0][dy];
            acc.x = fmaf(f[ 0 + fb], lft[dy], acc.x);
            acc.x = fmaf(f[ 1 + fb], mm.x,    acc.x);
            acc.x = fmaf(f[ 2 + fb], mm.y,    acc.x);

            acc.y = fmaf(f[ 9 + fb], mm.x,    acc.y);
            acc.y = fmaf(f[10 + fb], mm.y,    acc.y);
            acc.y = fmaf(f[11 + fb], mm.z,    acc.y);

            acc.z = fmaf(f[18 + fb], mm.y,    acc.z);
            acc.z = fmaf(f[19 + fb], mm.z,    acc.z);
            acc.z = fmaf(f[20 + fb], mm.w,    acc.z);

            acc.w = fmaf(f[27 + fb], mm.z,    acc.w);
            acc.w = fmaf(f[28 + fb], mm.w,    acc.w);
            acc.w = fmaf(f[29 + fb], rgt[dy], acc.w);
        }
        acc.x = fmaxf(acc.x, 0.f);
        acc.y = fmaxf(acc.y, 0.f);
        acc.z = fmaxf(acc.z, 0.f);
        acc.w = fmaxf(acc.w, 0.f);
        __builtin_nontemporal_store(acc, (f4*)(obase + (size_t)ci * plane));

        // rotate depth-4 pipeline (SSA rename) + issue ci+DEPTH
        if (ci + 1 < CH) {
#pragma unroll
            for (int d = 0; d < DEPTH - 1; ++d)
#pragma unroll
                for (int dy = 0; dy < 3; ++dy) m[d][dy] = m[d + 1][dy];
            if (ci + DEPTH < CH) {
                const float* qp = qbase + (size_t)(ci + DEPTH) * plane;
#pragma unroll
                for (int dy = 0; dy < 3; ++dy)
                    m[DEPTH - 1][dy] = *(const f4*)(qp + roff[dy]);
            }
        }
    }
}

extern "C" void kernel_launch(void* const* d_in, const int* in_sizes, int n_in,
                              void* d_out, int out_size, void* d_ws, size_t ws_size,
                              hipStream_t stream)
{
    const float* q  = (const float*)d_in[0];
    const float* df = (const float*)d_in[1];
    float* out = (float*)d_out;

    dynconv<<<NBLK, BLK, 0, stream>>>(q, df, out);
}